// Round 1
// baseline (103.898 us; speedup 1.0000x reference)
//
#include <hip/hip_runtime.h>

// YOLO-style loss, B=131072, GRID=7, CELLS=49, 11 floats/cell.
// outputs: (B,539) fp32 -> linear stream of 11-float cells (cell g at float 11g).
// target:  (B,2,4) fp32.
// Memory-bound: ~287 MB read -> ~46us floor @ 6.3 TB/s.

constexpr int BLOCK = 256;
constexpr int CPC = 1024;                       // cells per chunk (per block)
constexpr int FLOATS_PER_CHUNK = CPC * 11;      // 11264
constexpr int F4_PER_CHUNK = FLOATS_PER_CHUNK / 4;  // 2816
constexpr int F4_PER_THREAD = F4_PER_CHUNK / BLOCK; // 11
constexpr int TOTAL_CELLS = 131072 * 49;        // 6422528
constexpr int NCHUNKS = TOTAL_CELLS / CPC;      // 6272 (exact)

__global__ __launch_bounds__(BLOCK) void yolo_loss_kernel(
    const float* __restrict__ outputs,
    const float* __restrict__ target,
    double* __restrict__ acc)
{
#pragma clang fp contract(off)
    __shared__ float lds[FLOATS_PER_CHUNK];
    __shared__ double wred[BLOCK / 64];

    const int t = threadIdx.x;
    const unsigned chunk = blockIdx.x;

    // ---- stage 1024 cells (11264 floats) into LDS, 11 coalesced float4/thread
    const float4* src = reinterpret_cast<const float4*>(outputs)
                        + (size_t)chunk * F4_PER_CHUNK;
    float4* l4 = reinterpret_cast<float4*>(lds);
#pragma unroll
    for (int i = 0; i < F4_PER_THREAD; ++i)
        l4[t + BLOCK * i] = src[t + BLOCK * i];
    __syncthreads();

    const float4* tg4 = reinterpret_cast<const float4*>(target);
    const float CW = 1.0f / 7.0f;

    double a = 0.0;
#pragma unroll
    for (int q = 0; q < 4; ++q) {
        const int cl = t + BLOCK * q;               // cell within chunk
        const unsigned g = chunk * CPC + cl;        // global cell index
        const unsigned b = g / 49u;                 // sample
        const unsigned s = g - b * 49u;             // cell within sample
        const float xl = (float)(s % 7u) / 7.0f;    // exact fp32 div, matches numpy
        const float yl = (float)(s / 7u) / 7.0f;

        const float4 T0 = tg4[2u * b];
        const float4 T1 = tg4[2u * b + 1u];
        const bool v1 = (T1.x != -1.0f);

        const float* cp = lds + cl * 11;            // 11t base: coprime w/ 32 banks

        float conf0, conf1, term0, term1;
        bool one0, one1;
        {   // box j=0 (always valid)
            const float px = cp[0], py = cp[1], pw = cp[2], ph = cp[3], pc = cp[4];
            const float tx = T0.x, ty = T0.y, tw = T0.z, th = T0.w;
            const float ix = fabsf(fmaxf(px - 0.5f * pw, tx - 0.5f * tw)
                                 - fminf(px + 0.5f * pw, tx + 0.5f * tw));
            const float iy = fabsf(fmaxf(py - 0.5f * ph, ty - 0.5f * th)
                                 - fminf(py + 0.5f * ph, ty + 0.5f * th));
            const float inter = ix * iy;
            const float uni = pw * ph + tw * th - inter;
            conf0 = inter / uni;
            one0 = (xl <= tx) && (tx <= xl + CW) && (yl <= ty) && (ty <= yl + CW);
            const float d0 = tx - px, d1 = ty - py;
            const float d2 = sqrtf(tw) - sqrtf(pw);
            const float d3 = sqrtf(th) - sqrtf(ph);
            const float coord = ((d0 * d0 + d1 * d1) + d2 * d2) + d3 * d3;
            const float dc = conf0 - pc;
            term0 = one0 ? (5.0f * coord + dc * dc) : (0.5f * pc * pc);
        }
        {   // box j=1 (valid iff T1.x != -1)
            const float px = cp[5], py = cp[6], pw = cp[7], ph = cp[8], pc = cp[9];
            const float tx = T1.x, ty = T1.y, tw = T1.z, th = T1.w;
            const float ix = fabsf(fmaxf(px - 0.5f * pw, tx - 0.5f * tw)
                                 - fminf(px + 0.5f * pw, tx + 0.5f * tw));
            const float iy = fabsf(fmaxf(py - 0.5f * ph, ty - 0.5f * th)
                                 - fminf(py + 0.5f * ph, ty + 0.5f * th));
            const float inter = ix * iy;
            const float uni = pw * ph + tw * th - inter;
            conf1 = inter / uni;
            const bool inx = (xl <= tx) && (tx <= xl + CW);
            const bool iny = (yl <= ty) && (ty <= yl + CW);
            one1 = inx && iny && v1;
            const float d0 = tx - px, d1 = ty - py;
            const float d2 = sqrtf(tw) - sqrtf(pw);
            const float d3 = sqrtf(th) - sqrtf(ph);
            const float coord = ((d0 * d0 + d1 * d1) + d2 * d2) + d3 * d3;
            const float dc = conf1 - pc;
            term1 = one1 ? (5.0f * coord + dc * dc)
                         : (v1 ? (0.5f * pc * pc) : 0.0f);
        }
        // class term
        const float sum_conf = conf0 + (v1 ? conf1 : 0.0f);
        float cls = 0.0f;
        if (one0 || one1) {
            const float d = cp[10] - sum_conf;
            cls = d * d;
        }
        a += (double)term0 + (double)term1 + (double)cls;
    }

    // ---- reduction: wave shfl -> LDS -> block -> global fp64 atomic
#pragma unroll
    for (int off = 32; off > 0; off >>= 1)
        a += __shfl_down(a, off);
    if ((t & 63) == 0) wred[t >> 6] = a;
    __syncthreads();
    if (t == 0) {
        double s = wred[0] + wred[1] + wred[2] + wred[3];
        atomicAdd(acc, s);
    }
}

__global__ void finalize_kernel(const double* __restrict__ acc,
                                float* __restrict__ out)
{
    out[0] = (float)acc[0];
}

extern "C" void kernel_launch(void* const* d_in, const int* in_sizes, int n_in,
                              void* d_out, int out_size, void* d_ws, size_t ws_size,
                              hipStream_t stream)
{
    const float* outputs = (const float*)d_in[0];
    const float* target  = (const float*)d_in[1];
    float* out = (float*)d_out;
    double* acc = (double*)d_ws;

    hipMemsetAsync(acc, 0, sizeof(double), stream);
    yolo_loss_kernel<<<NCHUNKS, BLOCK, 0, stream>>>(outputs, target, acc);
    finalize_kernel<<<1, 1, 0, stream>>>(acc, out);
}